// Round 2
// baseline (826.988 us; speedup 1.0000x reference)
//
#include <hip/hip_runtime.h>

// GCN 3-layer forward on MI355X.
// Pipeline (A_hat (X W) = (A_hat X) W), layers 1+2 FUSED (gather -> reg-A-frag -> MFMA):
//   fused1: H1s = dinv*relu((A_hat X) W1 + b1)     [gather Xs rows, K=64]
//   fused2: H2  = relu((A_hat H1s) W2 + b2)        [gather H1s rows, K=256]
//   GEMM3:  G3  = dinv*(H2 W3)    aggout: out = dinv[c]*(sum G3[r]+G3[c]) + b3 (f32)
// Fused kernel: wave owns 16 dst rows; lane(ml,quad) accumulates gathered sum in f32
// regs laid out exactly as the MFMA A-fragment (A[ml][ks*32+quad*8+j]); converts to
// bf16 frags in-register; K-loop stages Bt slices (16KB) in LDS (m97 2-barrier pattern).
// Saves the Y1/Y2 HBM round-trips and the separate GEMM passes.
// Gather is at the random-fetch path ceiling (~3.7-3.8 TB/s TCC fill, measured r0/r1);
// FETCH floor for random graph over 8 XCD L2s is ~360MB -- no ordering can beat it.
// CSR build: round-3-proven (atomics only on memset-initialized arrays),
// rowidx clamped at read time.

#define IN_F 50
#define HID  256
#define OUT_F 121
#define KP1  64      // layer-1 width padded 50->64
#define NP3  128     // layer-3 N padded 121->128
#define MPAD 100096  // 782 * 128

typedef __attribute__((ext_vector_type(8))) short bf16x8;
typedef __attribute__((ext_vector_type(4))) float f32x4;

__device__ __forceinline__ float bf2f(unsigned short u) {
    union { unsigned int i; float f; } x; x.i = ((unsigned int)u) << 16; return x.f;
}
__device__ __forceinline__ unsigned short f2bf(float f) {
    union { float f; unsigned int i; } x; x.f = f;
    unsigned int r = x.i + 0x7FFFu + ((x.i >> 16) & 1u);  // RNE
    return (unsigned short)(r >> 16);
}

__device__ __forceinline__ void gl2lds16(const void* g, void* l) {
    __builtin_amdgcn_global_load_lds(
        (const __attribute__((address_space(1))) void*)g,
        (__attribute__((address_space(3))) void*)l, 16, 0, 0);
}

// ---- edge dtype detection (int64 vs int32), 64-lane parallel ----------------
__global__ void k_detect(const int* __restrict__ ei, int* __restrict__ flag, int N) {
    int i = threadIdx.x;
    int lo = ei[2 * i], hi = ei[2 * i + 1];
    int bad = (hi != 0) || ((unsigned)lo >= (unsigned)N);
    unsigned long long m = __ballot(bad);
    if (threadIdx.x == 0) *flag = (m == 0ULL) ? 1 : 0;
}

// ---- CSR build --------------------------------------------------------------

__global__ void k_count(const int* __restrict__ ei, const int* __restrict__ flag,
                        int* __restrict__ cnt, int E, int N) {
    int t = blockIdx.x * blockDim.x + threadIdx.x;
    if (t >= E) return;
    int f = *flag;
    int c = f ? ei[2 * (E + t)] : ei[E + t];
    c = min(max(c, 0), N - 1);
    atomicAdd(&cnt[c], 1);
}

__global__ __launch_bounds__(1024) void k_scan(const int* __restrict__ cnt,
                                               int* __restrict__ offs,
                                               float* __restrict__ dinv, int n) {
    __shared__ int wsum[16];
    __shared__ int s_carry;
    int lane = threadIdx.x & 63, wid = threadIdx.x >> 6;
    if (threadIdx.x == 0) s_carry = 0;
    __syncthreads();
    for (int base = 0; base < n; base += 4096) {
        int i0 = base + (int)threadIdx.x * 4;
        int v0 = (i0 + 0 < n) ? cnt[i0 + 0] : 0;
        int v1 = (i0 + 1 < n) ? cnt[i0 + 1] : 0;
        int v2 = (i0 + 2 < n) ? cnt[i0 + 2] : 0;
        int v3 = (i0 + 3 < n) ? cnt[i0 + 3] : 0;
        int s1 = v0 + v1, s2 = s1 + v2, tsum = s2 + v3;
        int x = tsum;
        #pragma unroll
        for (int d = 1; d < 64; d <<= 1) {
            int y = __shfl_up(x, d, 64);
            if (lane >= d) x += y;
        }
        if (lane == 63) wsum[wid] = x;
        __syncthreads();
        int wpre = 0;
        #pragma unroll
        for (int j = 0; j < 16; j++) wpre += (j < wid) ? wsum[j] : 0;
        int carry = s_carry;
        int e0 = carry + wpre + x - tsum;
        if (i0 + 0 < n) { offs[i0+0]=e0;    dinv[i0+0]=rsqrtf((float)(v0+1)); }
        if (i0 + 1 < n) { offs[i0+1]=e0+v0; dinv[i0+1]=rsqrtf((float)(v1+1)); }
        if (i0 + 2 < n) { offs[i0+2]=e0+s1; dinv[i0+2]=rsqrtf((float)(v2+1)); }
        if (i0 + 3 < n) { offs[i0+3]=e0+s2; dinv[i0+3]=rsqrtf((float)(v3+1)); }
        __syncthreads();
        if (threadIdx.x == 1023) s_carry = carry + wpre + x;
        __syncthreads();
    }
    if (threadIdx.x == 0) offs[n] = s_carry;
}

__global__ void k_fill(const int* __restrict__ ei, const int* __restrict__ flag,
                       const int* __restrict__ offs,
                       int* __restrict__ fillc, int* __restrict__ rowidx, int E, int N) {
    int t = blockIdx.x * blockDim.x + threadIdx.x;
    if (t >= E) return;
    int f = *flag;
    int c = f ? ei[2 * (E + t)] : ei[E + t];
    int r = f ? ei[2 * t] : ei[t];
    c = min(max(c, 0), N - 1);
    r = min(max(r, 0), N - 1);
    int pos = offs[c] + atomicAdd(&fillc[c], 1);
    if ((unsigned)pos < (unsigned)E) rowidx[pos] = r;
}

// ---- input prep -------------------------------------------------------------

__global__ void k_padx(const float* __restrict__ x, const float* __restrict__ dinv,
                       unsigned short* __restrict__ Xs, int N) {
    int idx = blockIdx.x * blockDim.x + threadIdx.x;
    if (idx >= N * KP1) return;
    int node = idx >> 6, k = idx & 63;
    Xs[idx] = (k < IN_F) ? f2bf(dinv[node] * x[node * IN_F + k]) : (unsigned short)0;
}

__global__ void k_tr(const float* __restrict__ W, unsigned short* __restrict__ Bt,
                     int K, int Nw, int Kp, int Np) {
    int idx = blockIdx.x * blockDim.x + threadIdx.x;
    if (idx >= Np * Kp) return;
    int nn = idx / Kp, k = idx - nn * Kp;
    Bt[idx] = (k < K && nn < Nw) ? f2bf(W[k * Nw + nn]) : (unsigned short)0;
}

__device__ __forceinline__ int rclamp(int r, int N) { return min(max(r, 0), N - 1); }

// ---- FUSED gather + GEMM ----------------------------------------------------
// C[g][0..255] = post( (sum_{src in list(g)} Hsrc[src] + Hsrc[g]) * dinv[g] @ Bt )
// K = K32*32 (64 or 256). Grid: MPAD/64 blocks x 256 thr (4 waves x 16 rows).
// Wave lane(ml,quad): accA[ks][j] = A[g=blk*64+w*16+ml][ks*32+quad*8+j]  (MFMA A-frag).
template<int K32, int SCALE>
__global__ __launch_bounds__(256) void k_fused(const unsigned short* __restrict__ Hsrc,
                                               const unsigned short* __restrict__ Bt,
                                               const int* __restrict__ offs,
                                               const int* __restrict__ rowidx,
                                               const float* __restrict__ dinv,
                                               const float* __restrict__ bias,
                                               unsigned short* __restrict__ Cout,
                                               int N) {
    __shared__ char lds[16384];   // B slice: 256 rows x 64B (32 k-elems bf16)
    const int K = K32 * 32;
    const int tid = threadIdx.x;
    const int wid = tid >> 6, lane = tid & 63;
    const int quad = lane >> 4, ml = lane & 15;
    const int g = blockIdx.x * 64 + wid * 16 + ml;   // this lane's A-row
    const int gc = min(g, N - 1);

    // ---- gather phase: accumulate self + neighbors into A-frag registers ----
    float accA[K32][8];
    {
        #pragma unroll
        for (int ks = 0; ks < K32; ks++) {
            bf16x8 v = *(const bf16x8*)(Hsrc + (size_t)gc * K + ks * 32 + quad * 8);
            #pragma unroll
            for (int j = 0; j < 8; j++) accA[ks][j] = bf2f((unsigned short)v[j]);
        }
    }
    int e = offs[gc], end = offs[gc + 1];
    if (g >= N) { e = 0; end = 0; }
    while (__any(e < end)) {
        int ec = min(e, max(end - 1, 0));
        int src = rclamp(rowidx[ec], N);
        float m = (e < end) ? 1.0f : 0.0f;
        bf16x8 u[K32];
        #pragma unroll
        for (int ks = 0; ks < K32; ks++)
            u[ks] = *(const bf16x8*)(Hsrc + (size_t)src * K + ks * 32 + quad * 8);
        #pragma unroll
        for (int ks = 0; ks < K32; ks++)
            #pragma unroll
            for (int j = 0; j < 8; j++)
                accA[ks][j] = fmaf(bf2f((unsigned short)u[ks][j]), m, accA[ks][j]);
        e++;
    }
    // scale by dinv[g] and convert to bf16 A-fragments
    float dv = dinv[gc];
    bf16x8 af[K32];
    #pragma unroll
    for (int ks = 0; ks < K32; ks++)
        #pragma unroll
        for (int j = 0; j < 8; j++) af[ks][j] = (short)f2bf(accA[ks][j] * dv);

    // ---- GEMM phase: K-loop over staged B slices ----
    f32x4 accC[16];
    #pragma unroll
    for (int nf = 0; nf < 16; nf++) accC[nf] = (f32x4){0.f, 0.f, 0.f, 0.f};

    for (int ks = 0; ks < K32; ks++) {
        __syncthreads();   // protect LDS from previous slice reads
        #pragma unroll
        for (int i = 0; i < 4; i++) {
            int c = i * 256 + tid;          // 1024 chunks of 16B
            int nn = c >> 2, q = c & 3;
            gl2lds16(Bt + (size_t)nn * K + ks * 32 + q * 8, lds + c * 16);
        }
        __syncthreads();   // drains vmcnt: LDS writes visible
        bf16x8 a;
        // select af[ks] with compile-time unrolled switch (keep regs, no scratch)
        #pragma unroll
        for (int s = 0; s < K32; s++) if (s == ks) a = af[s];
        #pragma unroll
        for (int nf = 0; nf < 16; nf++) {
            bf16x8 bfv = *(const bf16x8*)(lds + ((nf * 16 + ml) * 64 + quad * 16));
            accC[nf] = __builtin_amdgcn_mfma_f32_16x16x32_bf16(a, bfv, accC[nf], 0, 0, 0);
        }
    }

    // ---- epilogue: bias, relu, optional dinv scale, bf16 store ----
    int r0 = blockIdx.x * 64 + wid * 16 + quad * 4;
    float dd[4] = {1.f, 1.f, 1.f, 1.f};
    if (SCALE) { dd[0]=dinv[r0]; dd[1]=dinv[r0+1]; dd[2]=dinv[r0+2]; dd[3]=dinv[r0+3]; }
    #pragma unroll
    for (int nf = 0; nf < 16; nf++) {
        int col = nf * 16 + ml;
        float bb = bias[col];
        #pragma unroll
        for (int i = 0; i < 4; i++) {
            float v = accC[nf][i] + bb;
            v = fmaxf(v, 0.f);
            v *= dd[i];
            Cout[(size_t)(r0 + i) * HID + col] = f2bf(v);
        }
    }
}

// ---- LDS-tiled GEMM (m97 structure) — layer 3 only --------------------------
__global__ __launch_bounds__(256) void k_gemm_lds(const unsigned short* __restrict__ A,
                                                  const unsigned short* __restrict__ Bt,
                                                  const float* __restrict__ dinv,
                                                  const float* __restrict__ bias,
                                                  unsigned short* __restrict__ C,
                                                  int K, int Nout,
                                                  int BIAS, int RELU, int SCALE) {
    __shared__ char lds[16384];   // A tile [128][32] bf16 @0, B tile @8192
    const int tid = threadIdx.x;
    const int wid = tid >> 6, lane = tid & 63;
    const int wm = wid & 1, wn = wid >> 1;
    const int quad = lane >> 4, ml = lane & 15;
    const int m0 = blockIdx.x * 128;
    const int n0g = blockIdx.y * 128;

    f32x4 acc[4][4];
    #pragma unroll
    for (int a = 0; a < 4; a++)
        #pragma unroll
        for (int b = 0; b < 4; b++) acc[a][b] = (f32x4){0.f, 0.f, 0.f, 0.f};

    for (int kk = 0; kk < K; kk += 32) {
        #pragma unroll
        for (int r = 0; r < 2; r++) {
            int c = r * 256 + tid;            // chunk 0..511; row=c>>2, quarter=c&3
            int row = c >> 2, q = c & 3;
            gl2lds16(A  + (size_t)(m0  + row) * K + kk + q * 8, lds + c * 16);
            gl2lds16(Bt + (size_t)(n0g + row) * K + kk + q * 8, lds + 8192 + c * 16);
        }
        __syncthreads();   // drains vmcnt: LDS writes visible
        bf16x8 af[4], bfv[4];
        #pragma unroll
        for (int mf = 0; mf < 4; mf++)
            af[mf] = *(const bf16x8*)(lds + ((wm * 64 + mf * 16 + ml) * 64 + quad * 16));
        #pragma unroll
        for (int nf = 0; nf < 4; nf++)
            bfv[nf] = *(const bf16x8*)(lds + 8192 + ((wn * 64 + nf * 16 + ml) * 64 + quad * 16));
        #pragma unroll
        for (int mf = 0; mf < 4; mf++)
            #pragma unroll
            for (int nf = 0; nf < 4; nf++)
                acc[mf][nf] = __builtin_amdgcn_mfma_f32_16x16x32_bf16(af[mf], bfv[nf], acc[mf][nf], 0, 0, 0);
        __syncthreads();   // protect LDS before next stage
    }

    #pragma unroll
    for (int mf = 0; mf < 4; mf++) {
        int r0 = m0 + wm * 64 + mf * 16 + quad * 4;
        float dd[4] = {1.f, 1.f, 1.f, 1.f};
        if (SCALE) { dd[0]=dinv[r0]; dd[1]=dinv[r0+1]; dd[2]=dinv[r0+2]; dd[3]=dinv[r0+3]; }
        #pragma unroll
        for (int nf = 0; nf < 4; nf++) {
            int col = n0g + wn * 64 + nf * 16 + ml;
            float bb = BIAS ? bias[col] : 0.f;
            #pragma unroll
            for (int i = 0; i < 4; i++) {
                float v = acc[mf][nf][i] + bb;
                if (RELU) v = fmaxf(v, 0.f);
                v *= dd[i];
                C[(size_t)(r0 + i) * Nout + col] = f2bf(v);
            }
        }
    }
}

// ---- aggout: rows 128 bf16 = 256B -> 16 lanes/row, 4 nodes/wave -------------
__global__ void k_aggout(const unsigned short* __restrict__ G,
                         const int* __restrict__ offs, const int* __restrict__ rowidx,
                         const float* __restrict__ dinv, const float* __restrict__ bias,
                         float* __restrict__ out, int N) {
    int wid = threadIdx.x >> 6, lane = threadIdx.x & 63;
    int sub = lane >> 4, sl = lane & 15;
    int node = blockIdx.x * 16 + wid * 4 + sub;
    int nc = min(node, N - 1);
    int c = sl * 8;
    bf16x8 s = *(const bf16x8*)(G + (size_t)nc * NP3 + c);
    float a[8];
    #pragma unroll
    for (int k = 0; k < 8; k++) a[k] = bf2f((unsigned short)s[k]);
    int e = offs[nc], end = offs[nc + 1];
    if (node >= N) { e = 0; end = 0; }
    while (__any(e < end)) {
        int r[4]; float m[4];
        #pragma unroll
        for (int j = 0; j < 4; j++) {
            int idx = e + j;
            m[j] = (idx < end) ? 1.f : 0.f;
            idx = min(idx, end - 1); idx = max(idx, 0);
            r[j] = rclamp(rowidx[idx], N);
        }
        bf16x8 u[4];
        #pragma unroll
        for (int j = 0; j < 4; j++)
            u[j] = *(const bf16x8*)(G + (size_t)r[j] * NP3 + c);
        #pragma unroll
        for (int j = 0; j < 4; j++)
            #pragma unroll
            for (int k = 0; k < 8; k++)
                a[k] = fmaf(bf2f((unsigned short)u[j][k]), m[j], a[k]);
        e += 4;
    }
    if (node < N) {
        float dv = dinv[node];
        #pragma unroll
        for (int k = 0; k < 8; k++) {
            int col = c + k;
            if (col < OUT_F)
                out[(size_t)node * OUT_F + col] = fmaf(a[k], dv, bias[col]);
        }
    }
}

// ---- launch -----------------------------------------------------------------

extern "C" void kernel_launch(void* const* d_in, const int* in_sizes, int n_in,
                              void* d_out, int out_size, void* d_ws, size_t ws_size,
                              hipStream_t stream) {
    const float* x  = (const float*)d_in[0];
    const int*   ei = (const int*)d_in[1];
    const float* W1 = (const float*)d_in[2];
    const float* b1 = (const float*)d_in[3];
    const float* W2 = (const float*)d_in[4];
    const float* b2 = (const float*)d_in[5];
    const float* W3 = (const float*)d_in[6];
    const float* b3 = (const float*)d_in[7];
    float* out = (float*)d_out;

    const int N = in_sizes[0] / IN_F;     // 100000
    const int E = in_sizes[1] / 2;        // 1600000

    char* w = (char*)d_ws;
    size_t off = 0;
    auto alloc = [&](size_t bytes) -> char* {
        char* p = w + off;
        off += (bytes + 255) & ~(size_t)255;
        return p;
    };
    int*   cnt    = (int*)  alloc((size_t)N * 4);
    int*   offs   = (int*)  alloc((size_t)(N + 1) * 4);
    int*   fillc  = (int*)  alloc((size_t)N * 4);
    float* dinv   = (float*)alloc((size_t)MPAD * 4);   // padded: epilogues read r<MPAD
    int*   flag   = (int*)  alloc(256);
    int*   rowidx = (int*)  alloc((size_t)E * 4);
    unsigned short* Bt1 = (unsigned short*)alloc((size_t)HID * KP1 * 2);
    unsigned short* Bt2 = (unsigned short*)alloc((size_t)HID * HID * 2);
    unsigned short* Bt3 = (unsigned short*)alloc((size_t)NP3 * HID * 2);
    unsigned short* bufA = (unsigned short*)alloc((size_t)MPAD * HID * 2);  // Xs -> H2
    unsigned short* bufB = (unsigned short*)alloc((size_t)MPAD * HID * 2);  // H1s -> G3
    unsigned short* Xs  = bufA;
    unsigned short* H1s = bufB;   // fused1 out (can't alias Xs: random gather)
    unsigned short* H2  = bufA;   // fused2 out (Xs dead)
    unsigned short* G3  = bufB;   // gemm3 out (H1s dead)

    hipMemsetAsync(cnt, 0, (size_t)N * 4, stream);
    hipMemsetAsync(fillc, 0, (size_t)N * 4, stream);
    hipMemsetAsync(rowidx, 0, (size_t)E * 4, stream);

    k_detect<<<1, 64, 0, stream>>>(ei, flag, N);
    k_count<<<(E + 255) / 256, 256, 0, stream>>>(ei, flag, cnt, E, N);
    k_scan<<<1, 1024, 0, stream>>>(cnt, offs, dinv, N);
    k_fill<<<(E + 255) / 256, 256, 0, stream>>>(ei, flag, offs, fillc, rowidx, E, N);

    k_padx<<<(N * KP1 + 255) / 256, 256, 0, stream>>>(x, dinv, Xs, N);
    k_tr<<<(HID * KP1 + 255) / 256, 256, 0, stream>>>(W1, Bt1, IN_F, HID, KP1, HID);
    k_tr<<<(HID * HID + 255) / 256, 256, 0, stream>>>(W2, Bt2, HID, HID, HID, HID);
    k_tr<<<(NP3 * HID + 255) / 256, 256, 0, stream>>>(W3, Bt3, HID, OUT_F, HID, NP3);

    const int fgrid = MPAD / 64;       // 1564
    // layer 1 fused: gather Xs (K=64) -> GEMM W1 (+b1, relu, *dinv)
    k_fused<2, 1><<<fgrid, 256, 0, stream>>>(Xs, Bt1, offs, rowidx, dinv, b1, H1s, N);
    // layer 2 fused: gather H1s (K=256) -> GEMM W2 (+b2, relu)
    k_fused<8, 0><<<fgrid, 256, 0, stream>>>(H1s, Bt2, offs, rowidx, dinv, b2, H2, N);
    // layer 3: GEMM (*dinv), then aggregate (+b3), f32 out
    dim3 g3(MPAD / 128, NP3 / 128);    // (782, 1)
    k_gemm_lds<<<g3, 256, 0, stream>>>(H2, Bt3, dinv, b3, G3, HID, NP3, 0, 0, 1);
    k_aggout<<<(N + 15) / 16, 256, 0, stream>>>(G3, offs, rowidx, dinv, b3, out, N);

    (void)n_in; (void)out_size; (void)ws_size;
}

// Round 3
// 639.263 us; speedup vs baseline: 1.2937x; 1.2937x over previous
//
#include <hip/hip_runtime.h>

// GCN 3-layer forward on MI355X.
// Pipeline (A_hat (X W) = (A_hat X) W):
//   aggx:  Y1 = A_hat X         GEMM1: H1s = dinv*relu(Y1 W1 + b1)
//   agg256s: Y2 = A_hat H1      GEMM2: H2 = relu(Y2 W2 + b2)
//   GEMM3: G3 = dinv*(H2 W3)    aggouts: out = dinv[c]*(sum G3[r]+G3[c]) + b3 (f32)
// GEMM: m97-style LDS-tiled MFMA (128x128 tile, BK=32, global_load_lds w=16).
// Agg kernels: 16B/lane gathers, multi-node-per-wave, masked unroll-4.
// NEW this round: agg256s/aggouts are FEATURE-SPLIT + XCD-ALIGNED.
//   Measured r0-r2: agg256 FETCH invariant at ~402MB = 8 XCDs x full 51.2MB slab
//   (each XCD's L2 streams the whole source matrix; 3.8TB/s fill-path wall).
//   Fix: split features into L2-line chunks (128B) and pin chunk -> XCD via
//   blockIdx%8 (observed round-robin mapping). Per-XCD slab 51.2->12.8MB, so
//   FETCH ~402->~110MB. If the mapping assumption fails, perf returns to the
//   old value; correctness never depends on placement.
// CSR build: round-3-proven (atomics only on memset-initialized arrays),
// rowidx clamped at read time.

#define IN_F 50
#define HID  256
#define OUT_F 121
#define KP1  64      // layer-1 width padded 50->64
#define NP3  128     // layer-3 N padded 121->128
#define MPAD 100096  // 782 * 128

typedef __attribute__((ext_vector_type(8))) short bf16x8;
typedef __attribute__((ext_vector_type(4))) float f32x4;

__device__ __forceinline__ float bf2f(unsigned short u) {
    union { unsigned int i; float f; } x; x.i = ((unsigned int)u) << 16; return x.f;
}
__device__ __forceinline__ unsigned short f2bf(float f) {
    union { float f; unsigned int i; } x; x.f = f;
    unsigned int r = x.i + 0x7FFFu + ((x.i >> 16) & 1u);  // RNE
    return (unsigned short)(r >> 16);
}

__device__ __forceinline__ void gl2lds16(const void* g, void* l) {
    __builtin_amdgcn_global_load_lds(
        (const __attribute__((address_space(1))) void*)g,
        (__attribute__((address_space(3))) void*)l, 16, 0, 0);
}

// ---- edge dtype detection (int64 vs int32), 64-lane parallel ----------------
__global__ void k_detect(const int* __restrict__ ei, int* __restrict__ flag, int N) {
    int i = threadIdx.x;
    int lo = ei[2 * i], hi = ei[2 * i + 1];
    int bad = (hi != 0) || ((unsigned)lo >= (unsigned)N);
    unsigned long long m = __ballot(bad);
    if (threadIdx.x == 0) *flag = (m == 0ULL) ? 1 : 0;
}

// ---- CSR build --------------------------------------------------------------

__global__ void k_count(const int* __restrict__ ei, const int* __restrict__ flag,
                        int* __restrict__ cnt, int E, int N) {
    int t = blockIdx.x * blockDim.x + threadIdx.x;
    if (t >= E) return;
    int f = *flag;
    int c = f ? ei[2 * (E + t)] : ei[E + t];
    c = min(max(c, 0), N - 1);
    atomicAdd(&cnt[c], 1);
}

__global__ __launch_bounds__(1024) void k_scan(const int* __restrict__ cnt,
                                               int* __restrict__ offs,
                                               float* __restrict__ dinv, int n) {
    __shared__ int wsum[16];
    __shared__ int s_carry;
    int lane = threadIdx.x & 63, wid = threadIdx.x >> 6;
    if (threadIdx.x == 0) s_carry = 0;
    __syncthreads();
    for (int base = 0; base < n; base += 4096) {
        int i0 = base + (int)threadIdx.x * 4;
        int v0 = (i0 + 0 < n) ? cnt[i0 + 0] : 0;
        int v1 = (i0 + 1 < n) ? cnt[i0 + 1] : 0;
        int v2 = (i0 + 2 < n) ? cnt[i0 + 2] : 0;
        int v3 = (i0 + 3 < n) ? cnt[i0 + 3] : 0;
        int s1 = v0 + v1, s2 = s1 + v2, tsum = s2 + v3;
        int x = tsum;
        #pragma unroll
        for (int d = 1; d < 64; d <<= 1) {
            int y = __shfl_up(x, d, 64);
            if (lane >= d) x += y;
        }
        if (lane == 63) wsum[wid] = x;
        __syncthreads();
        int wpre = 0;
        #pragma unroll
        for (int j = 0; j < 16; j++) wpre += (j < wid) ? wsum[j] : 0;
        int carry = s_carry;
        int e0 = carry + wpre + x - tsum;
        if (i0 + 0 < n) { offs[i0+0]=e0;    dinv[i0+0]=rsqrtf((float)(v0+1)); }
        if (i0 + 1 < n) { offs[i0+1]=e0+v0; dinv[i0+1]=rsqrtf((float)(v1+1)); }
        if (i0 + 2 < n) { offs[i0+2]=e0+s1; dinv[i0+2]=rsqrtf((float)(v2+1)); }
        if (i0 + 3 < n) { offs[i0+3]=e0+s2; dinv[i0+3]=rsqrtf((float)(v3+1)); }
        __syncthreads();
        if (threadIdx.x == 1023) s_carry = carry + wpre + x;
        __syncthreads();
    }
    if (threadIdx.x == 0) offs[n] = s_carry;
}

__global__ void k_fill(const int* __restrict__ ei, const int* __restrict__ flag,
                       const int* __restrict__ offs,
                       int* __restrict__ fillc, int* __restrict__ rowidx, int E, int N) {
    int t = blockIdx.x * blockDim.x + threadIdx.x;
    if (t >= E) return;
    int f = *flag;
    int c = f ? ei[2 * (E + t)] : ei[E + t];
    int r = f ? ei[2 * t] : ei[t];
    c = min(max(c, 0), N - 1);
    r = min(max(r, 0), N - 1);
    int pos = offs[c] + atomicAdd(&fillc[c], 1);
    if ((unsigned)pos < (unsigned)E) rowidx[pos] = r;
}

// ---- input prep -------------------------------------------------------------

__global__ void k_padx(const float* __restrict__ x, const float* __restrict__ dinv,
                       unsigned short* __restrict__ Xs, int N) {
    int idx = blockIdx.x * blockDim.x + threadIdx.x;
    if (idx >= N * KP1) return;
    int node = idx >> 6, k = idx & 63;
    Xs[idx] = (k < IN_F) ? f2bf(dinv[node] * x[node * IN_F + k]) : (unsigned short)0;
}

__global__ void k_tr(const float* __restrict__ W, unsigned short* __restrict__ Bt,
                     int K, int Nw, int Kp, int Np) {
    int idx = blockIdx.x * blockDim.x + threadIdx.x;
    if (idx >= Np * Kp) return;
    int nn = idx / Kp, k = idx - nn * Kp;
    Bt[idx] = (k < K && nn < Nw) ? f2bf(W[k * Nw + nn]) : (unsigned short)0;
}

// ---- LDS-tiled GEMM (m97 structure) -----------------------------------------
__global__ __launch_bounds__(256) void k_gemm_lds(const unsigned short* __restrict__ A,
                                                  const unsigned short* __restrict__ Bt,
                                                  const float* __restrict__ dinv,
                                                  const float* __restrict__ bias,
                                                  unsigned short* __restrict__ C,
                                                  int K, int Nout,
                                                  int BIAS, int RELU, int SCALE) {
    __shared__ char lds[16384];   // A tile [128][32] bf16 @0, B tile @8192
    const int tid = threadIdx.x;
    const int wid = tid >> 6, lane = tid & 63;
    const int wm = wid & 1, wn = wid >> 1;
    const int quad = lane >> 4, ml = lane & 15;
    const int m0 = blockIdx.x * 128;
    const int n0g = blockIdx.y * 128;

    f32x4 acc[4][4];
    #pragma unroll
    for (int a = 0; a < 4; a++)
        #pragma unroll
        for (int b = 0; b < 4; b++) acc[a][b] = (f32x4){0.f, 0.f, 0.f, 0.f};

    for (int kk = 0; kk < K; kk += 32) {
        #pragma unroll
        for (int r = 0; r < 2; r++) {
            int c = r * 256 + tid;            // chunk 0..511; row=c>>2, quarter=c&3
            int row = c >> 2, q = c & 3;
            gl2lds16(A  + (size_t)(m0  + row) * K + kk + q * 8, lds + c * 16);
            gl2lds16(Bt + (size_t)(n0g + row) * K + kk + q * 8, lds + 8192 + c * 16);
        }
        __syncthreads();   // drains vmcnt: LDS writes visible
        bf16x8 af[4], bfv[4];
        #pragma unroll
        for (int mf = 0; mf < 4; mf++)
            af[mf] = *(const bf16x8*)(lds + ((wm * 64 + mf * 16 + ml) * 64 + quad * 16));
        #pragma unroll
        for (int nf = 0; nf < 4; nf++)
            bfv[nf] = *(const bf16x8*)(lds + 8192 + ((wn * 64 + nf * 16 + ml) * 64 + quad * 16));
        #pragma unroll
        for (int mf = 0; mf < 4; mf++)
            #pragma unroll
            for (int nf = 0; nf < 4; nf++)
                acc[mf][nf] = __builtin_amdgcn_mfma_f32_16x16x32_bf16(af[mf], bfv[nf], acc[mf][nf], 0, 0, 0);
        __syncthreads();   // protect LDS before next stage
    }

    #pragma unroll
    for (int mf = 0; mf < 4; mf++) {
        int r0 = m0 + wm * 64 + mf * 16 + quad * 4;
        float dd[4] = {1.f, 1.f, 1.f, 1.f};
        if (SCALE) { dd[0]=dinv[r0]; dd[1]=dinv[r0+1]; dd[2]=dinv[r0+2]; dd[3]=dinv[r0+3]; }
        #pragma unroll
        for (int nf = 0; nf < 4; nf++) {
            int col = n0g + wn * 64 + nf * 16 + ml;
            float bb = BIAS ? bias[col] : 0.f;
            #pragma unroll
            for (int i = 0; i < 4; i++) {
                float v = acc[mf][nf][i] + bb;
                if (RELU) v = fmaxf(v, 0.f);
                v *= dd[i];
                C[(size_t)(r0 + i) * Nout + col] = f2bf(v);
            }
        }
    }
}

// ---- aggregation kernels ----------------------------------------------------
// 16B/lane gathers, masked unroll-4 edge loop (tail lanes re-read last edge row
// -> L1 hit; fma-masked with 0).

__device__ __forceinline__ int rclamp(int r, int N) { return min(max(r, 0), N - 1); }

// aggx: rows 64 bf16 = 128B (1 L2 line, can't feature-split) -> 8 lanes/row,
// 8 nodes/wave, 32 nodes/block.
__global__ void k_aggx(const unsigned short* __restrict__ Xs,
                       const int* __restrict__ offs, const int* __restrict__ rowidx,
                       const float* __restrict__ dinv, unsigned short* __restrict__ Y, int N) {
    int wid = threadIdx.x >> 6, lane = threadIdx.x & 63;
    int sub = lane >> 3, sl = lane & 7;
    int node = blockIdx.x * 32 + wid * 8 + sub;
    int nc = min(node, N - 1);
    int c = sl * 8;
    bf16x8 s = *(const bf16x8*)(Xs + (size_t)nc * KP1 + c);
    float a[8];
    #pragma unroll
    for (int k = 0; k < 8; k++) a[k] = bf2f((unsigned short)s[k]);
    int e = offs[nc], end = offs[nc + 1];
    if (node >= N) { e = 0; end = 0; }
    while (__any(e < end)) {
        int r[4]; float m[4];
        #pragma unroll
        for (int j = 0; j < 4; j++) {
            int idx = e + j;
            m[j] = (idx < end) ? 1.f : 0.f;
            idx = min(idx, end - 1); idx = max(idx, 0);
            r[j] = rclamp(rowidx[idx], N);
        }
        bf16x8 u[4];
        #pragma unroll
        for (int j = 0; j < 4; j++)
            u[j] = *(const bf16x8*)(Xs + (size_t)r[j] * KP1 + c);
        #pragma unroll
        for (int j = 0; j < 4; j++)
            #pragma unroll
            for (int k = 0; k < 8; k++)
                a[k] = fmaf(bf2f((unsigned short)u[j][k]), m[j], a[k]);
        e += 4;
    }
    if (node < N) {
        float dv = dinv[node];
        bf16x8 o;
        #pragma unroll
        for (int k = 0; k < 8; k++) o[k] = (short)f2bf(a[k] * dv);
        *(bf16x8*)(Y + (size_t)node * KP1 + c) = o;
    }
}

// agg256s: FEATURE-SPLIT gather for 256-wide rows. F=4 chunks of 64 bf16 (128B).
// cell = blockIdx.x & 7 (presumed XCD): chunk = cell>>1, dest-half = cell&1.
// Per wave: 8 lanes/chunk-row, 8 chunk-rows (sub), 32/block. Each XCD's L2 only
// streams one 12.8MB quarter-slab of Hn.
__global__ void k_agg256s(const unsigned short* __restrict__ Hn,
                          const int* __restrict__ offs, const int* __restrict__ rowidx,
                          const float* __restrict__ dinv, unsigned short* __restrict__ Y,
                          int N, int half_n) {
    int cell = blockIdx.x & 7;
    int chunk = cell >> 1, half = cell & 1;
    int idx = blockIdx.x >> 3;
    int wid = threadIdx.x >> 6, lane = threadIdx.x & 63;
    int sub = lane >> 3, sl = lane & 7;
    int node = half * half_n + idx * 32 + wid * 8 + sub;
    int hi_end = min((half + 1) * half_n, N);
    int ok = node < hi_end;
    int nc = ok ? node : hi_end - 1;
    int c = chunk * 64 + sl * 8;
    bf16x8 s = *(const bf16x8*)(Hn + (size_t)nc * HID + c);
    float a[8];
    #pragma unroll
    for (int k = 0; k < 8; k++) a[k] = bf2f((unsigned short)s[k]);
    int e = offs[nc], end = offs[nc + 1];
    if (!ok) { e = 0; end = 0; }
    while (__any(e < end)) {
        int r[4]; float m[4];
        #pragma unroll
        for (int j = 0; j < 4; j++) {
            int idx2 = e + j;
            m[j] = (idx2 < end) ? 1.f : 0.f;
            idx2 = min(idx2, end - 1); idx2 = max(idx2, 0);
            r[j] = rclamp(rowidx[idx2], N);
        }
        bf16x8 u[4];
        #pragma unroll
        for (int j = 0; j < 4; j++)
            u[j] = *(const bf16x8*)(Hn + (size_t)r[j] * HID + c);
        #pragma unroll
        for (int j = 0; j < 4; j++)
            #pragma unroll
            for (int k = 0; k < 8; k++)
                a[k] = fmaf(bf2f((unsigned short)u[j][k]), m[j], a[k]);
        e += 4;
    }
    if (ok) {
        float dv = dinv[node];
        bf16x8 o;
        #pragma unroll
        for (int k = 0; k < 8; k++) o[k] = (short)f2bf(a[k] * dv);
        *(bf16x8*)(Y + (size_t)node * HID + c) = o;
    }
}

// aggouts: FEATURE-SPLIT gather for 128-wide rows. F=2 chunks of 64 bf16 (128B).
// cell = blockIdx.x & 7: chunk = cell>>2, dest-quarter = cell&3.
__global__ void k_aggouts(const unsigned short* __restrict__ G,
                          const int* __restrict__ offs, const int* __restrict__ rowidx,
                          const float* __restrict__ dinv, const float* __restrict__ bias,
                          float* __restrict__ out, int N, int quar_n) {
    int cell = blockIdx.x & 7;
    int chunk = cell >> 2, quar = cell & 3;
    int idx = blockIdx.x >> 3;
    int wid = threadIdx.x >> 6, lane = threadIdx.x & 63;
    int sub = lane >> 3, sl = lane & 7;
    int node = quar * quar_n + idx * 32 + wid * 8 + sub;
    int hi_end = min((quar + 1) * quar_n, N);
    int ok = node < hi_end;
    int nc = ok ? node : hi_end - 1;
    int c = chunk * 64 + sl * 8;
    bf16x8 s = *(const bf16x8*)(G + (size_t)nc * NP3 + c);
    float a[8];
    #pragma unroll
    for (int k = 0; k < 8; k++) a[k] = bf2f((unsigned short)s[k]);
    int e = offs[nc], end = offs[nc + 1];
    if (!ok) { e = 0; end = 0; }
    while (__any(e < end)) {
        int r[4]; float m[4];
        #pragma unroll
        for (int j = 0; j < 4; j++) {
            int idx2 = e + j;
            m[j] = (idx2 < end) ? 1.f : 0.f;
            idx2 = min(idx2, end - 1); idx2 = max(idx2, 0);
            r[j] = rclamp(rowidx[idx2], N);
        }
        bf16x8 u[4];
        #pragma unroll
        for (int j = 0; j < 4; j++)
            u[j] = *(const bf16x8*)(G + (size_t)r[j] * NP3 + c);
        #pragma unroll
        for (int j = 0; j < 4; j++)
            #pragma unroll
            for (int k = 0; k < 8; k++)
                a[k] = fmaf(bf2f((unsigned short)u[j][k]), m[j], a[k]);
        e += 4;
    }
    if (ok) {
        float dv = dinv[node];
        #pragma unroll
        for (int k = 0; k < 8; k++) {
            int col = c + k;
            if (col < OUT_F)
                out[(size_t)node * OUT_F + col] = fmaf(a[k], dv, bias[col]);
        }
    }
}

// ---- launch -----------------------------------------------------------------

extern "C" void kernel_launch(void* const* d_in, const int* in_sizes, int n_in,
                              void* d_out, int out_size, void* d_ws, size_t ws_size,
                              hipStream_t stream) {
    const float* x  = (const float*)d_in[0];
    const int*   ei = (const int*)d_in[1];
    const float* W1 = (const float*)d_in[2];
    const float* b1 = (const float*)d_in[3];
    const float* W2 = (const float*)d_in[4];
    const float* b2 = (const float*)d_in[5];
    const float* W3 = (const float*)d_in[6];
    const float* b3 = (const float*)d_in[7];
    float* out = (float*)d_out;

    const int N = in_sizes[0] / IN_F;     // 100000
    const int E = in_sizes[1] / 2;        // 1600000

    char* w = (char*)d_ws;
    size_t off = 0;
    auto alloc = [&](size_t bytes) -> char* {
        char* p = w + off;
        off += (bytes + 255) & ~(size_t)255;
        return p;
    };
    int*   cnt    = (int*)  alloc((size_t)N * 4);
    int*   offs   = (int*)  alloc((size_t)(N + 1) * 4);
    int*   fillc  = (int*)  alloc((size_t)N * 4);
    float* dinv   = (float*)alloc((size_t)MPAD * 4);   // padded: epilogues read r<MPAD
    int*   flag   = (int*)  alloc(256);
    int*   rowidx = (int*)  alloc((size_t)E * 4);
    unsigned short* Bt1 = (unsigned short*)alloc((size_t)HID * KP1 * 2);
    unsigned short* Bt2 = (unsigned short*)alloc((size_t)HID * HID * 2);
    unsigned short* Bt3 = (unsigned short*)alloc((size_t)NP3 * HID * 2);
    unsigned short* bufA = (unsigned short*)alloc((size_t)MPAD * HID * 2);  // Xs -> H1s -> H2
    unsigned short* bufB = (unsigned short*)alloc((size_t)MPAD * HID * 2);  // Y1 -> Y2 -> G3
    unsigned short* Xs  = bufA;
    unsigned short* Y1  = bufB;
    unsigned short* H1s = bufA;
    unsigned short* Y2  = bufB;
    unsigned short* H2  = bufA;
    unsigned short* G3  = bufB;

    hipMemsetAsync(cnt, 0, (size_t)N * 4, stream);
    hipMemsetAsync(fillc, 0, (size_t)N * 4, stream);
    hipMemsetAsync(rowidx, 0, (size_t)E * 4, stream);

    k_detect<<<1, 64, 0, stream>>>(ei, flag, N);
    k_count<<<(E + 255) / 256, 256, 0, stream>>>(ei, flag, cnt, E, N);
    k_scan<<<1, 1024, 0, stream>>>(cnt, offs, dinv, N);
    k_fill<<<(E + 255) / 256, 256, 0, stream>>>(ei, flag, offs, fillc, rowidx, E, N);

    k_padx<<<(N * KP1 + 255) / 256, 256, 0, stream>>>(x, dinv, Xs, N);
    k_tr<<<(HID * KP1 + 255) / 256, 256, 0, stream>>>(W1, Bt1, IN_F, HID, KP1, HID);
    k_tr<<<(HID * HID + 255) / 256, 256, 0, stream>>>(W2, Bt2, HID, HID, HID, HID);
    k_tr<<<(NP3 * HID + 255) / 256, 256, 0, stream>>>(W3, Bt3, HID, OUT_F, HID, NP3);

    dim3 g12(MPAD / 128, HID / 128);   // (782, 2)
    dim3 g3(MPAD / 128, NP3 / 128);    // (782, 1)

    int half_n = (N + 1) / 2;                    // 50000
    int bpc2 = (half_n + 31) / 32;               // 1563
    int quar_n = (N + 3) / 4;                    // 25000
    int bpc3 = (quar_n + 31) / 32;               // 782

    // layer 1: aggregate-first, then GEMM (+b1, relu, *dinv)
    k_aggx<<<(N + 31) / 32, 256, 0, stream>>>(Xs, offs, rowidx, dinv, Y1, N);
    k_gemm_lds<<<g12, 256, 0, stream>>>(Y1, Bt1, dinv, b1, H1s, KP1, HID, 1, 1, 1);
    // layer 2: feature-split aggregate H1s, then GEMM (+b2, relu)
    k_agg256s<<<8 * bpc2, 256, 0, stream>>>(H1s, offs, rowidx, dinv, Y2, N, half_n);
    k_gemm_lds<<<g12, 256, 0, stream>>>(Y2, Bt2, dinv, b2, H2, HID, HID, 1, 1, 0);
    // layer 3: GEMM (*dinv), then feature-split aggregate (+b3), f32 out
    k_gemm_lds<<<g3, 256, 0, stream>>>(H2, Bt3, dinv, b3, G3, HID, NP3, 0, 0, 1);
    k_aggouts<<<8 * bpc3, 256, 0, stream>>>(G3, offs, rowidx, dinv, b3, out, N, quar_n);

    (void)n_in; (void)out_size; (void)ws_size;
}